// Round 11
// baseline (193.376 us; speedup 1.0000x reference)
//
#include <hip/hip_runtime.h>
#include <math.h>

// BertBidafAttention B=16, CL=512, QL=64, H=768 — 3-launch pipeline.
// K1/K2: verified R10 versions (189.4 us). K3 change this round: h-slices of 48
// -> grid (16,16) = 256 blocks = one block per CU (was 192 blocks, 64 CUs idle).
// LDS 94.7 KB. Phase C uses 3 of 4 wl-slots (wl==3 stages+barriers only); phase D
// tn loops 0..2. All MFMA k-orders unchanged -> bit-identical output.

#define B_  16
#define CL_ 512
#define QL_ 64
#define H_  768
#define M_  (B_ * CL_)   // 8192

typedef __attribute__((ext_vector_type(8))) short s8v;   // 8 bf16
typedef __attribute__((ext_vector_type(4))) float f4v;   // MFMA acc

__device__ __forceinline__ unsigned short bf16_rne(float x) {
    unsigned int u = __float_as_uint(x);
    u += 0x7fffu + ((u >> 16) & 1u);
    return (unsigned short)(u >> 16);
}
__device__ __forceinline__ float bf16_f(unsigned short h) {
    return __uint_as_float((unsigned int)h << 16);
}
__device__ __forceinline__ void split2(float x, unsigned short& h, unsigned short& l) {
    h = bf16_rne(x);
    l = bf16_rne(x - bf16_f(h));
}

// ---------- K1: u = q @ W (split-bf16; W staged+transposed+split in DB LDS,
//                1 barrier/iter, reg-prefetched) + beta blocks (blockIdx.x >= 192) ----------
__global__ __launch_bounds__(256) void k_u_beta(const float* __restrict__ q,
    const float* __restrict__ W, const float* __restrict__ bias,
    unsigned short* __restrict__ uh, unsigned short* __restrict__ ul,
    float* __restrict__ beta)
{
    if (blockIdx.x >= 192) {
        const int row = (blockIdx.x - 192) * 4 + (threadIdx.x >> 6);
        const int lane = threadIdx.x & 63;
        float p = 0.f;
        for (int d = lane; d < H_; d += 64) p = fmaf(bias[d], q[(size_t)row * H_ + d], p);
#pragma unroll
        for (int o = 32; o; o >>= 1) p += __shfl_xor(p, o);
        if (lane == 0) beta[row] = p;
        return;
    }
    __shared__ unsigned short Wh[2][64][40], Wl[2][64][40];
    const int m0 = (blockIdx.x & 15) * 64, n0 = (blockIdx.x >> 4) * 64;
    const int t = threadIdx.x, w = t >> 6, lane = t & 63;
    const int fm = lane & 15, quad = lane >> 4;
    const int mrow = m0 + w * 16 + fm;
    const int dd = t >> 3, hc = (t & 7) * 8;
    f4v acc[4];
#pragma unroll
    for (int j = 0; j < 4; ++j) acc[j] = (f4v){0.f, 0.f, 0.f, 0.f};
    // preload tile 0 (W) and fragment 0 (q)
    const float* wp0 = &W[(size_t)dd * H_ + n0 + hc];
    float4 v0 = *(const float4*)wp0, v1 = *(const float4*)(wp0 + 4);
    const float* ap0 = &q[(size_t)mrow * H_ + quad * 8];
    float4 a0 = *(const float4*)ap0, a1 = *(const float4*)(ap0 + 4);
    int p = 0;
    for (int k0 = 0; k0 < H_; k0 += 32) {
        // split current regs into LDS (W) and frags (q)
        const float ws_[8] = {v0.x, v0.y, v0.z, v0.w, v1.x, v1.y, v1.z, v1.w};
#pragma unroll
        for (int j = 0; j < 8; ++j) {
            unsigned short h, l; split2(ws_[j], h, l);
            Wh[p][hc + j][dd] = h; Wl[p][hc + j][dd] = l;
        }
        const float as[8] = {a0.x, a0.y, a0.z, a0.w, a1.x, a1.y, a1.z, a1.w};
        s8v fah, fal;
#pragma unroll
        for (int j = 0; j < 8; ++j) { unsigned short h, l; split2(as[j], h, l); fah[j] = (short)h; fal[j] = (short)l; }
        __syncthreads();
        // prefetch next tile/fragment (overlaps the MFMA cluster below)
        if (k0 + 32 < H_) {
            const float* wp = &W[(size_t)(k0 + 32 + dd) * H_ + n0 + hc];
            v0 = *(const float4*)wp; v1 = *(const float4*)(wp + 4);
            const float* ap = &q[(size_t)mrow * H_ + k0 + 32 + quad * 8];
            a0 = *(const float4*)ap; a1 = *(const float4*)(ap + 4);
        }
#pragma unroll
        for (int tn = 0; tn < 4; ++tn) {
            const s8v bh = *(const s8v*)&Wh[p][tn * 16 + fm][quad * 8];
            const s8v bl = *(const s8v*)&Wl[p][tn * 16 + fm][quad * 8];
            acc[tn] = __builtin_amdgcn_mfma_f32_16x16x32_bf16(fah, bh, acc[tn], 0, 0, 0);
            acc[tn] = __builtin_amdgcn_mfma_f32_16x16x32_bf16(fah, bl, acc[tn], 0, 0, 0);
            acc[tn] = __builtin_amdgcn_mfma_f32_16x16x32_bf16(fal, bh, acc[tn], 0, 0, 0);
        }
        p ^= 1;
    }
#pragma unroll
    for (int tn = 0; tn < 4; ++tn) {
        const int col = n0 + tn * 16 + fm;
#pragma unroll
        for (int r = 0; r < 4; ++r) {
            const int row = m0 + w * 16 + quad * 4 + r;
            unsigned short h, l; split2(acc[tn][r], h, l);
            uh[(size_t)row * H_ + col] = h;
            ul[(size_t)row * H_ + col] = l;
        }
    }
}

// ---------- K2: s = c @ u^T + beta; 32-row tiles, 512 threads, BK=64.
//   8 waves: wave w -> msub=(w>>2)*16, ntile=(w&3)*16 (16x16 acc each).
//   Staging: 512 thr x float4 = 32x64 c-chunk per barrier (12 barriers).
//   Epilogue: row softmax -> s1, transposed raw s -> sT[b][q][c]. ----------
__global__ __launch_bounds__(512) void k_s_sm(const float* __restrict__ c,
    const unsigned short* __restrict__ uh, const unsigned short* __restrict__ ul,
    const float* __restrict__ beta, const int* __restrict__ q_mask,
    float* __restrict__ sT, unsigned short* __restrict__ s1)
{
    __shared__ unsigned short chh[2][32][72], cll[2][32][72];
    __shared__ float sL[32][65];
    const int m0 = blockIdx.x * 32;
    const int batch = m0 >> 9;
    const int cloc = m0 & (CL_ - 1);
    const int t = threadIdx.x, w = t >> 6, lane = t & 63;
    const int fm = lane & 15, quad = lane >> 4;
    const int msub = (w >> 2) * 16, ntile = (w & 3) * 16;
    const int srow = t >> 4, sc4 = (t & 15) * 4;   // staging: 32 rows x 64 k, 4 floats/thread
    f4v acc = (f4v){0.f, 0.f, 0.f, 0.f};

    const size_t urow = (size_t)(batch * QL_ + ntile + fm) * H_;

    float4 v = *(const float4*)&c[(size_t)(m0 + srow) * H_ + sc4];
    int p = 0;
    for (int k0 = 0; k0 < H_; k0 += 64) {
        ushort4 hh, ll;
        split2(v.x, hh.x, ll.x); split2(v.y, hh.y, ll.y);
        split2(v.z, hh.z, ll.z); split2(v.w, hh.w, ll.w);
        *(ushort4*)&chh[p][srow][sc4] = hh;
        *(ushort4*)&cll[p][srow][sc4] = ll;
        __syncthreads();
        if (k0 + 64 < H_) v = *(const float4*)&c[(size_t)(m0 + srow) * H_ + k0 + 64 + sc4];
#pragma unroll
        for (int kk = 0; kk < 2; ++kk) {
            const s8v fah = *(const s8v*)&chh[p][msub + fm][kk * 32 + quad * 8];
            const s8v fal = *(const s8v*)&cll[p][msub + fm][kk * 32 + quad * 8];
            const s8v bh = *(const s8v*)&uh[urow + k0 + kk * 32 + quad * 8];
            const s8v bl = *(const s8v*)&ul[urow + k0 + kk * 32 + quad * 8];
            acc = __builtin_amdgcn_mfma_f32_16x16x32_bf16(fah, bh, acc, 0, 0, 0);
            acc = __builtin_amdgcn_mfma_f32_16x16x32_bf16(fah, bl, acc, 0, 0, 0);
            acc = __builtin_amdgcn_mfma_f32_16x16x32_bf16(fal, bh, acc, 0, 0, 0);
        }
        p ^= 1;
    }
    // epilogue: fill sL tile (32 x 64)
    {
        const int col = ntile + fm;
        const float bb = beta[batch * QL_ + col];
#pragma unroll
        for (int r = 0; r < 4; ++r)
            sL[msub + quad * 4 + r][col] = acc[r] + bb;
    }
    __syncthreads();
    // row softmax over q (64 cols); wave w handles rows 4w..4w+3 of 32
    const bool qm = q_mask[batch * QL_ + lane] != 0;
#pragma unroll
    for (int rr = 0; rr < 4; ++rr) {
        const int lr = w * 4 + rr;
        const float x = qm ? sL[lr][lane] : -1e30f;
        float mx = x;
#pragma unroll
        for (int o = 32; o; o >>= 1) mx = fmaxf(mx, __shfl_xor(mx, o));
        const float e = __expf(x - mx);
        float sm = e;
#pragma unroll
        for (int o = 32; o; o >>= 1) sm += __shfl_xor(sm, o);
        s1[(size_t)(m0 + lr) * QL_ + lane] = bf16_rne(e / sm);
    }
    // transposed raw-s write: sT[b][q][cloc..cloc+31]
    {
        const int qq = t >> 3, c4o = (t & 7) * 4;
        float4 ov;
        ov.x = sL[c4o + 0][qq];
        ov.y = sL[c4o + 1][qq];
        ov.z = sL[c4o + 2][qq];
        ov.w = sL[c4o + 3][qq];
        *(float4*)&sT[((size_t)batch * QL_ + qq) * CL_ + cloc + c4o] = ov;
    }
}

// ---------- K3: fused colSM + t + finalize, 512 threads, grid (16 h-slices of 48, 16 b).
//   A) colSM from sT -> s2L (LDS bf16, XOR-swz), 8 q-rows per wave (full 512 c)
//   B) stage qT[48][..]
//   C) t-slice = s2^T @ c, K split across 2 wave-groups (grp), 3 h-tiles over wl 0..2
//      (wl==3 stages+barriers only); partial accs merged via LDS
//   D) finalize all 512 c-rows (64/wave), tn 0..2 over the 48-wide h-slice ----------
__global__ __launch_bounds__(512) void k_tfin3(const float* __restrict__ sT,
    const unsigned short* __restrict__ s1, const float* __restrict__ q,
    const float* __restrict__ c, const int* __restrict__ c_mask,
    float* __restrict__ out)
{
    __shared__ unsigned short s2L[64 * 512];      // colSM result, XOR-swizzled (65536 B)
    __shared__ unsigned short Bs[2][2][48][40];   // c^T staging, [grp][dbuf]   (15360 B)
    __shared__ unsigned short qT[48][72];         // q^T bf16 (h x q)            (6912 B)
    __shared__ unsigned short tT[48][72];         // t   bf16 (h x q)            (6912 B)
    const int h0 = blockIdx.x * 48;
    const int b  = blockIdx.y;
    const int t = threadIdx.x, w = t >> 6, lane = t & 63;
    const int fm = lane & 15, quad = lane >> 4;
    const int grp = w >> 2;        // K-half: 0 -> d0 in [0,256), 1 -> [256,512)
    const int wl  = w & 3;         // h-tile 0..2 (wl==3 idle in C-MFMA)

    // hoisted first c-tile load for phase C (in flight during phases A/B)
    const int tl = t & 255;                 // thread id within group
    const int cdd = tl >> 3;                // 0..31 d-row
    const int chc = (tl & 7) * 6;           // 0..42, 6 h-cols per thread
    const int gbase = grp * 256;            // this group's K offset
    const float* cp0 = &c[((size_t)b * CL_ + gbase + cdd) * H_ + h0 + chc];
    float2 cv0 = *(const float2*)cp0, cv1 = *(const float2*)(cp0 + 2), cv2 = *(const float2*)(cp0 + 4);

    // ---- phase A: column softmax (over c) for batch b -> s2L (8 q-rows/wave) ----
    {
        const int cbase8 = lane * 8;
        int cm8[8];
#pragma unroll
        for (int j = 0; j < 8; ++j) cm8[j] = c_mask[b * CL_ + cbase8 + j];
        const float* stb = sT + (size_t)b * QL_ * CL_;
#pragma unroll
        for (int qi = 0; qi < 8; ++qi) {
            const int qq = w * 8 + qi;
            const float* sr = stb + (size_t)qq * CL_ + cbase8;
            const float4 v0 = *(const float4*)sr, v1 = *(const float4*)(sr + 4);
            float x[8] = {v0.x, v0.y, v0.z, v0.w, v1.x, v1.y, v1.z, v1.w};
#pragma unroll
            for (int j = 0; j < 8; ++j) x[j] = cm8[j] ? x[j] : -1e30f;
            float m = x[0];
#pragma unroll
            for (int j = 1; j < 8; ++j) m = fmaxf(m, x[j]);
#pragma unroll
            for (int o = 32; o; o >>= 1) m = fmaxf(m, __shfl_xor(m, o));
            float e[8], sm = 0.f;
#pragma unroll
            for (int j = 0; j < 8; ++j) { e[j] = __expf(x[j] - m); sm += e[j]; }
#pragma unroll
            for (int o = 32; o; o >>= 1) sm += __shfl_xor(sm, o);
            const float inv = 1.f / sm;
            s8v sv;
#pragma unroll
            for (int j = 0; j < 8; ++j) sv[j] = (short)bf16_rne(e[j] * inv);
            const int boff = ((qq * 512 + cbase8) * 2) ^ ((qq & 7) << 4);
            *(s8v*)((char*)s2L + boff) = sv;
        }
    }

    // ---- phase B: stage q^T (512 threads, 6 h-cols x 1 q-row each) ----
    {
        const int qr = t >> 3;            // 0..63
        const int qc = (t & 7) * 6;       // 0..42
        const float* qp = &q[((size_t)b * QL_ + qr) * H_ + h0 + qc];
        const float2 u0 = *(const float2*)qp, u1 = *(const float2*)(qp + 2), u2 = *(const float2*)(qp + 4);
        qT[qc + 0][qr] = bf16_rne(u0.x); qT[qc + 1][qr] = bf16_rne(u0.y);
        qT[qc + 2][qr] = bf16_rne(u1.x); qT[qc + 3][qr] = bf16_rne(u1.y);
        qT[qc + 4][qr] = bf16_rne(u2.x); qT[qc + 5][qr] = bf16_rne(u2.y);
    }

    // ---- phase C: t-slice = (s2^T @ c), K split across wave-groups ----
    f4v acc[4];
#pragma unroll
    for (int j = 0; j < 4; ++j) acc[j] = (f4v){0.f, 0.f, 0.f, 0.f};
    {
        int p = 0;
        for (int d0 = 0; d0 < 256; d0 += 32) {
            const float xs[6] = {cv0.x, cv0.y, cv1.x, cv1.y, cv2.x, cv2.y};
#pragma unroll
            for (int j = 0; j < 6; ++j) Bs[grp][p][chc + j][cdd] = bf16_rne(xs[j]);
            __syncthreads();   // first iteration also orders phase-A/B LDS writes
            if (d0 + 32 < 256) {
                const float* cp = &c[((size_t)b * CL_ + gbase + d0 + 32 + cdd) * H_ + h0 + chc];
                cv0 = *(const float2*)cp; cv1 = *(const float2*)(cp + 2); cv2 = *(const float2*)(cp + 4);
            }
            if (wl < 3) {
                const s8v fb = *(const s8v*)&Bs[grp][p][wl * 16 + fm][quad * 8];
#pragma unroll
                for (int tm = 0; tm < 4; ++tm) {
                    const int boff = (((tm * 16 + fm) * 512 + gbase + d0 + quad * 8) * 2) ^ ((fm & 7) << 4);
                    const s8v fa = *(const s8v*)((const char*)s2L + boff);
                    acc[tm] = __builtin_amdgcn_mfma_f32_16x16x32_bf16(fa, fb, acc[tm], 0, 0, 0);
                }
            }
            p ^= 1;
        }
    }
    __syncthreads();   // all s2L/Bs reads done before reusing s2L as dump area
    // merge group partials: grp1 dumps f32 accs into (dead) s2L, grp0 sums -> tT
    {
        float* dumpf = (float*)s2L;   // needs 12 KB of the 64 KB region
        if (grp == 1 && wl < 3) {
#pragma unroll
            for (int tm = 0; tm < 4; ++tm)
#pragma unroll
                for (int r = 0; r < 4; ++r)
                    dumpf[((wl * 4 + tm) * 4 + r) * 64 + lane] = acc[tm][r];
        }
        __syncthreads();
        if (grp == 0 && wl < 3) {
#pragma unroll
            for (int tm = 0; tm < 4; ++tm)
#pragma unroll
                for (int r = 0; r < 4; ++r)
                    tT[wl * 16 + fm][tm * 16 + quad * 4 + r] =
                        bf16_rne(acc[tm][r] + dumpf[((wl * 4 + tm) * 4 + r) * 64 + lane]);
        }
    }
    __syncthreads();

    // ---- phase D: finalize all 512 c-rows, one 64-row chunk per wave, tn 0..2 ----
    {
        const int cbase = w * 64;
        f4v aa[4][3], bb[4][3];
#pragma unroll
        for (int i = 0; i < 4; ++i)
#pragma unroll
            for (int j = 0; j < 3; ++j) { aa[i][j] = (f4v){0.f, 0.f, 0.f, 0.f}; bb[i][j] = aa[i][j]; }
#pragma unroll
        for (int ks = 0; ks < 2; ++ks) {
            s8v fa[4], fq[3], ft[3];
#pragma unroll
            for (int tm = 0; tm < 4; ++tm)
                fa[tm] = *(const s8v*)&s1[(size_t)(b * CL_ + cbase + tm * 16 + fm) * QL_ + ks * 32 + quad * 8];
#pragma unroll
            for (int tn = 0; tn < 3; ++tn) {
                fq[tn] = *(const s8v*)&qT[tn * 16 + fm][ks * 32 + quad * 8];
                ft[tn] = *(const s8v*)&tT[tn * 16 + fm][ks * 32 + quad * 8];
            }
#pragma unroll
            for (int tm = 0; tm < 4; ++tm)
#pragma unroll
                for (int tn = 0; tn < 3; ++tn) {
                    aa[tm][tn] = __builtin_amdgcn_mfma_f32_16x16x32_bf16(fa[tm], fq[tn], aa[tm][tn], 0, 0, 0);
                    bb[tm][tn] = __builtin_amdgcn_mfma_f32_16x16x32_bf16(fa[tm], ft[tn], bb[tm][tn], 0, 0, 0);
                }
        }
#pragma unroll
        for (int tm = 0; tm < 4; ++tm)
#pragma unroll
            for (int tn = 0; tn < 3; ++tn) {
                const int h = h0 + tn * 16 + fm;
#pragma unroll
                for (int r = 0; r < 4; ++r) {
                    const int crow = cbase + tm * 16 + quad * 4 + r;
                    const float cv = c[((size_t)b * CL_ + crow) * H_ + h];
                    const float av = aa[tm][tn][r], bv = bb[tm][tn][r];
                    float* ob = out + (size_t)(b * CL_ + crow) * (4 * H_);
                    ob[h]           = cv;
                    ob[H_ + h]      = av;
                    ob[2 * H_ + h]  = cv * av;
                    ob[3 * H_ + h]  = cv * bv;
                }
            }
    }
}

extern "C" void kernel_launch(void* const* d_in, const int* in_sizes, int n_in,
                              void* d_out, int out_size, void* d_ws, size_t ws_size,
                              hipStream_t stream) {
    const float* c      = (const float*)d_in[0];
    const float* q      = (const float*)d_in[1];
    const int*   c_mask = (const int*)d_in[2];
    const int*   q_mask = (const int*)d_in[3];
    const float* W      = (const float*)d_in[4];
    const float* bias   = (const float*)d_in[5];
    float* out = (float*)d_out;

    // workspace — total 6295552 B (~6.0 MB)
    char* base = (char*)d_ws;
    unsigned short* uh   = (unsigned short*)(base);               // 1572864
    unsigned short* ul   = (unsigned short*)(base + 1572864);     // 1572864
    float*          beta = (float*)(base + 3145728);              // 4096
    float*          sT   = (float*)(base + 3149824);              // 2097152 (f32 [16][64][512])
    unsigned short* s1   = (unsigned short*)(base + 5246976);     // 1048576

    k_u_beta <<<dim3(192 + 256), dim3(256), 0, stream>>>(q, W, bias, uh, ul, beta);
    k_s_sm   <<<dim3(256),       dim3(512), 0, stream>>>(c, uh, ul, beta, q_mask, sT, s1);
    k_tfin3  <<<dim3(16, 16),    dim3(512), 0, stream>>>(sT, s1, q, c, c_mask, out);
}